// Round 9
// baseline (391.937 us; speedup 1.0000x reference)
//
#include <hip/hip_runtime.h>

#define BN_EPS 1e-5f

typedef short s8v __attribute__((ext_vector_type(8)));
typedef float f4v __attribute__((ext_vector_type(4)));
typedef unsigned short u4v __attribute__((ext_vector_type(4)));

__device__ __forceinline__ unsigned short f2bf(float f) {
  union { float f; unsigned u; } v; v.f = f;
  unsigned r = v.u + 0x7FFF + ((v.u >> 16) & 1);
  return (unsigned short)(r >> 16);
}
__device__ __forceinline__ float bf2f(unsigned short u) {
  union { unsigned u; float f; } v; v.u = ((unsigned)u) << 16; return v.f;
}

// ---------------------------------------------------------------- degree histogram (int)
__global__ __launch_bounds__(256) void deg_kernel(const int* __restrict__ dst,
                                                  int* __restrict__ deg, int E) {
  int e = blockIdx.x * 256 + threadIdx.x;
  if (e < E) atomicAdd(&deg[dst[e]], 1);
}

// ------------------------------------------- scan pass 1: per-block (1024 elems) totals
__global__ __launch_bounds__(256) void scan_partial_kernel(const int* __restrict__ deg,
    int* __restrict__ partials, int N) {
  __shared__ int sh[256];
  int t = threadIdx.x;
  int base = blockIdx.x * 1024 + t * 4;
  int s = 0;
#pragma unroll
  for (int i = 0; i < 4; ++i) {
    int idx = base + i;
    if (idx < N) s += deg[idx];
  }
  sh[t] = s;
  __syncthreads();
  for (int d = 128; d > 0; d >>= 1) {
    if (t < d) sh[t] += sh[t + d];
    __syncthreads();
  }
  if (t == 0) partials[blockIdx.x] = sh[0];
}

// ------------------------------------------- scan pass 2: exclusive scan of partials
__global__ __launch_bounds__(256) void scan_offsets_kernel(const int* __restrict__ partials,
    int* __restrict__ blk_off, int G) {
  __shared__ int sh[256];
  int t = threadIdx.x;
  sh[t] = (t < G) ? partials[t] : 0;
  __syncthreads();
  for (int d = 1; d < 256; d <<= 1) {
    int v = (t >= d) ? sh[t - d] : 0;
    __syncthreads();
    sh[t] += v;
    __syncthreads();
  }
  if (t < G) blk_off[t] = (t == 0) ? 0 : sh[t - 1];
}

// ----- scan pass 3: block-local exclusive scan + offset -> row_start, bucket cursors
__global__ __launch_bounds__(256) void scan_scatter_kernel(const int* __restrict__ deg,
    const int* __restrict__ blk_off, int* __restrict__ row_start,
    int* __restrict__ gcursor, int N) {
  __shared__ int sh[256];
  int t = threadIdx.x;
  int base = blockIdx.x * 1024 + t * 4;
  int v[4];
#pragma unroll
  for (int i = 0; i < 4; ++i) v[i] = (base + i < N) ? deg[base + i] : 0;
  sh[t] = v[0] + v[1] + v[2] + v[3];
  __syncthreads();
  for (int d = 1; d < 256; d <<= 1) {
    int u = (t >= d) ? sh[t - d] : 0;
    __syncthreads();
    sh[t] += u;
    __syncthreads();
  }
  int off = blk_off[blockIdx.x] + ((t == 0) ? 0 : sh[t - 1]);
#pragma unroll
  for (int i = 0; i < 4; ++i) {
    int idx = base + i;
    if (idx < N) {
      row_start[idx] = off;
      if ((idx & 127) == 0) gcursor[idx >> 7] = off;  // pairs cursor = CSR bucket start
      off += v[i];
    }
  }
}

// ------------------- CSR phase A: LDS-staged bucket scatter (kills partial-line writes)
#define CHUNK 8192
#define NBMAX 512
__global__ __launch_bounds__(256) void csr_bucket_kernel(
    const int* __restrict__ src, const int* __restrict__ dst,
    int* __restrict__ gcursor, unsigned* __restrict__ pairs, int E) {
  __shared__ int h[NBMAX];
  __shared__ int off[NBMAX];
  __shared__ int cnt2[NBMAX];
  __shared__ int gadj[NBMAX];
  __shared__ unsigned pbuf[CHUNK];
  __shared__ unsigned short bidx[CHUNK];
  int t = threadIdx.x;
  int base = blockIdx.x * CHUNK;
  int cnt = min(CHUNK, E - base);
  for (int i = t; i < NBMAX; i += 256) { h[i] = 0; cnt2[i] = 0; }
  __syncthreads();
  for (int i = t; i < cnt; i += 256) atomicAdd(&h[dst[base + i] >> 7], 1);
  __syncthreads();
  off[t] = h[t]; off[t + 256] = h[t + 256];
  __syncthreads();
  for (int d = 1; d < 512; d <<= 1) {
    int v0 = (t >= d) ? off[t - d] : 0;
    int v1 = off[t + 256 - d];
    __syncthreads();
    off[t] += v0; off[t + 256] += v1;
    __syncthreads();
  }
  int e0 = off[t] - h[t];
  int e1 = off[t + 256] - h[t + 256];
  __syncthreads();
  off[t] = e0; off[t + 256] = e1;
  __syncthreads();
  for (int i = t; i < NBMAX; i += 256) {
    int c = h[i];
    if (c > 0) gadj[i] = atomicAdd(&gcursor[i], c) - off[i];
  }
  __syncthreads();
  for (int i = t; i < cnt; i += 256) {
    int s = src[base + i];
    int d = dst[base + i];
    int b = d >> 7;
    int p = off[b] + atomicAdd(&cnt2[b], 1);
    pbuf[p] = (unsigned)s | ((unsigned)d << 16);   // both < 2^16 (N=50000)
    bidx[p] = (unsigned short)b;
  }
  __syncthreads();
  for (int i = t; i < cnt; i += 256)
    pairs[gadj[bidx[i]] + i] = pbuf[i];
}

// ------------------- CSR phase B: one block per bucket, private eidx region, LDS cursors
__global__ __launch_bounds__(256) void csr_fill_kernel(
    const unsigned* __restrict__ pairs, const int* __restrict__ row_start,
    int* __restrict__ eidx, int N, int E) {
  __shared__ int cur[128];
  int b = blockIdx.x;
  int node0 = b << 7;
  int t = threadIdx.x;
  if (t < 128) {
    int node = node0 + t;
    cur[t] = (node < N) ? row_start[node] : 0;
  }
  __syncthreads();
  int pbeg = row_start[node0];
  int pend = (node0 + 128 < N) ? row_start[node0 + 128] : E;
  for (int i = pbeg + t; i < pend; i += 256) {
    unsigned p = pairs[i];
    int pos = atomicAdd(&cur[(int)(p >> 16) - node0], 1);
    eidx[pos] = (int)(p & 0xFFFFu);
  }
}

// --------------- fused prep: xcast (blocks [0,xblocks)) + 6 weight transposes
__global__ __launch_bounds__(256) void prep_kernel(
    const float* __restrict__ x, unsigned short* __restrict__ xb,
    const float* __restrict__ Wl1, const float* __restrict__ Wr1,
    const float* __restrict__ Wl2, const float* __restrict__ Wr2,
    const float* __restrict__ W1, const float* __restrict__ W2,
    unsigned short* __restrict__ Wl1t, unsigned short* __restrict__ Wr1t,
    unsigned short* __restrict__ Wl2t, unsigned short* __restrict__ Wr2t,
    unsigned short* __restrict__ W1t, unsigned short* __restrict__ W2t,
    int N, int xblocks) {
  int blk = blockIdx.x;
  if (blk < xblocks) {
    int t = blk * 256 + threadIdx.x;
    if (t < N * 128) {
      int col = t & 127;
      int n = t >> 7;
      xb[t] = (col < 100) ? f2bf(x[n * 100 + col]) : (unsigned short)0;
    }
    return;
  }
  int w = blk - xblocks;
  const float* W; unsigned short* Wt; int K, C, base;
  if (w < 64)       { W = Wl1; Wt = Wl1t; K = 100; C = 128; base = 0;   }
  else if (w < 128) { W = Wr1; Wt = Wr1t; K = 100; C = 128; base = 64;  }
  else if (w < 192) { W = Wl2; Wt = Wl2t; K = 128; C = 128; base = 128; }
  else if (w < 256) { W = Wr2; Wt = Wr2t; K = 128; C = 128; base = 192; }
  else if (w < 320) { W = W1;  Wt = W1t;  K = 128; C = 128; base = 256; }
  else              { W = W2;  Wt = W2t;  K = 128; C = 64;  base = 320; }
  int t = (w - base) * 256 + threadIdx.x;
  if (t >= C * 128) return;
  int c = t >> 7;
  int k = t & 127;
  Wt[t] = (k < K) ? f2bf(W[k * C + c]) : (unsigned short)0;
}

// ------------------------------------------ gather mean over bf16 rows (1 wave / node)
__global__ __launch_bounds__(256) void gather_kernel(
    const unsigned short* __restrict__ feat, const int* __restrict__ eidx,
    const int* __restrict__ row_start, const int* __restrict__ deg,
    unsigned short* __restrict__ mean_out, int N) {
  int wave = threadIdx.x >> 6;
  int lane = threadIdx.x & 63;
  int node = blockIdx.x * 4 + wave;
  if (node >= N) return;
  int beg = row_start[node];
  int d = deg[node];
  float a0 = 0.0f, a1 = 0.0f;
  for (int i0 = 0; i0 < d; i0 += 64) {
    int cnt = min(64, d - i0);
    int my = (lane < cnt) ? eidx[beg + i0 + lane] : 0;
    int j = 0;
    for (; j + 7 < cnt; j += 8) {
      int s0 = __shfl(my, j + 0);
      int s1 = __shfl(my, j + 1);
      int s2 = __shfl(my, j + 2);
      int s3 = __shfl(my, j + 3);
      int s4 = __shfl(my, j + 4);
      int s5 = __shfl(my, j + 5);
      int s6 = __shfl(my, j + 6);
      int s7 = __shfl(my, j + 7);
      unsigned v0 = ((const unsigned*)(feat + (size_t)s0 * 128))[lane];
      unsigned v1 = ((const unsigned*)(feat + (size_t)s1 * 128))[lane];
      unsigned v2 = ((const unsigned*)(feat + (size_t)s2 * 128))[lane];
      unsigned v3 = ((const unsigned*)(feat + (size_t)s3 * 128))[lane];
      unsigned v4 = ((const unsigned*)(feat + (size_t)s4 * 128))[lane];
      unsigned v5 = ((const unsigned*)(feat + (size_t)s5 * 128))[lane];
      unsigned v6 = ((const unsigned*)(feat + (size_t)s6 * 128))[lane];
      unsigned v7 = ((const unsigned*)(feat + (size_t)s7 * 128))[lane];
      a0 += bf2f((unsigned short)v0) + bf2f((unsigned short)v1)
          + bf2f((unsigned short)v2) + bf2f((unsigned short)v3)
          + bf2f((unsigned short)v4) + bf2f((unsigned short)v5)
          + bf2f((unsigned short)v6) + bf2f((unsigned short)v7);
      a1 += bf2f((unsigned short)(v0 >> 16)) + bf2f((unsigned short)(v1 >> 16))
          + bf2f((unsigned short)(v2 >> 16)) + bf2f((unsigned short)(v3 >> 16))
          + bf2f((unsigned short)(v4 >> 16)) + bf2f((unsigned short)(v5 >> 16))
          + bf2f((unsigned short)(v6 >> 16)) + bf2f((unsigned short)(v7 >> 16));
    }
    for (; j < cnt; ++j) {
      int s0 = __shfl(my, j);
      unsigned v0 = ((const unsigned*)(feat + (size_t)s0 * 128))[lane];
      a0 += bf2f((unsigned short)v0);
      a1 += bf2f((unsigned short)(v0 >> 16));
    }
  }
  float inv = 1.0f / fmaxf((float)d, 1.0f);
  unsigned o = (unsigned)f2bf(a0 * inv) | ((unsigned)f2bf(a1 * inv) << 16);
  ((unsigned*)(mean_out + (size_t)node * 128))[lane] = o;
}

// --------------------- wave-independent MFMA GEMM: 16 rows/wave, NO block LDS tile,
// NO barriers (except one tiny one for STATS). Direct D-layout stores (64B segments).
// R8 lesson: 64-row LDS-staged blocks were latency-bound (MfmaUtil 3%, occ 24%).
template<int CT, bool DUAL, bool RELU, bool F32OUT, bool BF16OUT, bool STATS>
__global__ __launch_bounds__(256) void wgemm_kernel(
    const unsigned short* __restrict__ A1, const unsigned short* __restrict__ W1t,
    const unsigned short* __restrict__ A2, const unsigned short* __restrict__ W2t,
    const float* __restrict__ bias,
    float* __restrict__ outF, unsigned short* __restrict__ outB,
    float* __restrict__ sum, float* __restrict__ sq, int N) {
  const int COLS = CT * 16;
  __shared__ float red[STATS ? 8 * COLS : 1];   // [0..4*COLS) sums, [4*COLS..) sumsq
  int t = threadIdx.x;
  int wave = t >> 6, lane = t & 63;
  int quad = lane >> 4, m = lane & 15;
  int r0 = blockIdx.x * 64 + wave * 16;
  int ar = min(r0 + m, N - 1);                  // clamped A row (stores are guarded)

  f4v acc[CT];
#pragma unroll
  for (int ct = 0; ct < CT; ++ct) acc[ct] = (f4v){0.f, 0.f, 0.f, 0.f};

  const unsigned short* a1p = A1 + (size_t)ar * 128 + quad * 8;
  const unsigned short* a2p = DUAL ? (A2 + (size_t)ar * 128 + quad * 8) : nullptr;
#pragma unroll
  for (int k0 = 0; k0 < 128; k0 += 32) {
    s8v a1 = *(const s8v*)(a1p + k0);
    s8v a2;
    if (DUAL) a2 = *(const s8v*)(a2p + k0);
#pragma unroll
    for (int ct = 0; ct < CT; ++ct) {
      s8v b1 = *(const s8v*)(W1t + (size_t)(ct * 16 + m) * 128 + k0 + quad * 8);
      acc[ct] = __builtin_amdgcn_mfma_f32_16x16x32_bf16(a1, b1, acc[ct], 0, 0, 0);
      if (DUAL) {
        s8v b2 = *(const s8v*)(W2t + (size_t)(ct * 16 + m) * 128 + k0 + quad * 8);
        acc[ct] = __builtin_amdgcn_mfma_f32_16x16x32_bf16(a2, b2, acc[ct], 0, 0, 0);
      }
    }
  }
  // direct epilogue from D-layout: col = ct*16+m, row = quad*4+r
#pragma unroll
  for (int ct = 0; ct < CT; ++ct) {
    int col = ct * 16 + m;
    float b = bias[col];
    float s_ct = 0.0f, ss_ct = 0.0f;
#pragma unroll
    for (int r = 0; r < 4; ++r) {
      int gr = r0 + quad * 4 + r;
      float v = acc[ct][r] + b;
      if (RELU) v = fmaxf(v, 0.0f);
      if (gr < N) {
        if (F32OUT) outF[(size_t)gr * COLS + col] = v;
        if (BF16OUT) outB[(size_t)gr * COLS + col] = f2bf(v);
        if (STATS) { s_ct += v; ss_ct += v * v; }
      }
    }
    if (STATS) {
      s_ct += __shfl_xor(s_ct, 16);  s_ct += __shfl_xor(s_ct, 32);
      ss_ct += __shfl_xor(ss_ct, 16); ss_ct += __shfl_xor(ss_ct, 32);
      if (quad == 0) {
        red[wave * COLS + col] = s_ct;
        red[4 * COLS + wave * COLS + col] = ss_ct;
      }
    }
  }
  if (STATS) {
    __syncthreads();
    if (t < COLS) {
      float S = 0.0f, SS = 0.0f;
#pragma unroll
      for (int w = 0; w < 4; ++w) {
        S  += red[w * COLS + t];
        SS += red[4 * COLS + w * COLS + t];
      }
      int slot = (blockIdx.x & 7) * COLS + t;
      atomicAdd(&sum[slot], S);
      atomicAdd(&sq[slot], SS);
    }
  }
}

// ------------- fused sage2 + MLP1, wave-independent (16 rows/wave):
// h2 = relu(mean@Wl2 + h1b@Wr2 + bl2) -> fp32 direct store; D->A transpose through a
// PRIVATE per-wave 4.3KB LDS strip (no barrier; same-wave lgkmcnt only);
// y1 = h2b@W1 + b1 -> bf16 direct store + col stats (shfl + 1 barrier).
__global__ __launch_bounds__(256) void sage_mlp_kernel(
    const unsigned short* __restrict__ A1,   // mean2b
    const unsigned short* __restrict__ Wlt,
    const unsigned short* __restrict__ A2,   // h1b (self)
    const unsigned short* __restrict__ Wrt,
    const float* __restrict__ bl,
    const unsigned short* __restrict__ W1t, const float* __restrict__ b1,
    float* __restrict__ h2out, unsigned short* __restrict__ y1b,
    float* __restrict__ sum, float* __restrict__ sq, int N) {
  const int TS = 136;                        // bf16 strip stride: 16B-aligned rows
  __shared__ unsigned short tb[4][16 * TS];  // 17408 B, per-wave private
  __shared__ float red[8 * 128];             // 4096 B stats staging
  int t = threadIdx.x;
  int wave = t >> 6, lane = t & 63;
  int quad = lane >> 4, m = lane & 15;
  int r0 = blockIdx.x * 64 + wave * 16;
  int ar = min(r0 + m, N - 1);

  // ---- phase 1: sage2 dual GEMM
  f4v acc[8];
#pragma unroll
  for (int ct = 0; ct < 8; ++ct) acc[ct] = (f4v){0.f, 0.f, 0.f, 0.f};
  {
    const unsigned short* a1p = A1 + (size_t)ar * 128 + quad * 8;
    const unsigned short* a2p = A2 + (size_t)ar * 128 + quad * 8;
#pragma unroll
    for (int k0 = 0; k0 < 128; k0 += 32) {
      s8v a1 = *(const s8v*)(a1p + k0);
      s8v a2 = *(const s8v*)(a2p + k0);
#pragma unroll
      for (int ct = 0; ct < 8; ++ct) {
        s8v b1 = *(const s8v*)(Wlt + (size_t)(ct * 16 + m) * 128 + k0 + quad * 8);
        acc[ct] = __builtin_amdgcn_mfma_f32_16x16x32_bf16(a1, b1, acc[ct], 0, 0, 0);
        s8v b2 = *(const s8v*)(Wrt + (size_t)(ct * 16 + m) * 128 + k0 + quad * 8);
        acc[ct] = __builtin_amdgcn_mfma_f32_16x16x32_bf16(a2, b2, acc[ct], 0, 0, 0);
      }
    }
  }
  // ---- epilogue 1: h2 fp32 direct store + bf16 into private strip (local row = quad*4+r)
#pragma unroll
  for (int ct = 0; ct < 8; ++ct) {
    int col = ct * 16 + m;
    float b = bl[col];
#pragma unroll
    for (int r = 0; r < 4; ++r) {
      int lr = quad * 4 + r;
      int gr = r0 + lr;
      float v = fmaxf(acc[ct][r] + b, 0.0f);
      if (gr < N) h2out[(size_t)gr * 128 + col] = v;
      tb[wave][lr * TS + col] = f2bf(v);
    }
  }
  // ---- D->A transpose read (same wave; compiler inserts lgkmcnt wait)
  s8v af[4];
#pragma unroll
  for (int kk = 0; kk < 4; ++kk)
    af[kk] = *(const s8v*)&tb[wave][m * TS + kk * 32 + quad * 8];

  // ---- phase 2: y1 = h2b @ W1 + b1 (reuse acc)
#pragma unroll
  for (int ct = 0; ct < 8; ++ct) acc[ct] = (f4v){0.f, 0.f, 0.f, 0.f};
#pragma unroll
  for (int kk = 0; kk < 4; ++kk) {
    int k0 = kk * 32;
#pragma unroll
    for (int ct = 0; ct < 8; ++ct) {
      s8v bv = *(const s8v*)(W1t + (size_t)(ct * 16 + m) * 128 + k0 + quad * 8);
      acc[ct] = __builtin_amdgcn_mfma_f32_16x16x32_bf16(af[kk], bv, acc[ct], 0, 0, 0);
    }
  }
  // ---- epilogue 2: y1b bf16 direct store + col stats
#pragma unroll
  for (int ct = 0; ct < 8; ++ct) {
    int col = ct * 16 + m;
    float b = b1[col];
    float s_ct = 0.0f, ss_ct = 0.0f;
#pragma unroll
    for (int r = 0; r < 4; ++r) {
      int gr = r0 + quad * 4 + r;
      float v = acc[ct][r] + b;
      if (gr < N) {
        y1b[(size_t)gr * 128 + col] = f2bf(v);
        s_ct += v; ss_ct += v * v;
      }
    }
    s_ct += __shfl_xor(s_ct, 16);  s_ct += __shfl_xor(s_ct, 32);
    ss_ct += __shfl_xor(ss_ct, 16); ss_ct += __shfl_xor(ss_ct, 32);
    if (quad == 0) {
      red[wave * 128 + col] = s_ct;
      red[512 + wave * 128 + col] = ss_ct;
    }
  }
  __syncthreads();
  if (t < 128) {
    float S = red[t] + red[128 + t] + red[256 + t] + red[384 + t];
    float SS = red[512 + t] + red[640 + t] + red[768 + t] + red[896 + t];
    int slot = (blockIdx.x & 7) * 128 + t;
    atomicAdd(&sum[slot], S);
    atomicAdd(&sq[slot], SS);
  }
}

// --------- BN (train) + ReLU: bf16 in -> bf16 out (C = 128, 8 stat slots), 4 elems/thr
__global__ __launch_bounds__(256) void bn_relu_kernel(const unsigned short* __restrict__ y,
    int N, const float* __restrict__ sum, const float* __restrict__ sumsq,
    const float* __restrict__ g, const float* __restrict__ be,
    unsigned short* __restrict__ yb) {
  int t4 = blockIdx.x * 256 + threadIdx.x;
  if (t4 >= N * 32) return;
  int col0 = (t4 & 31) * 4;
  float invN = 1.0f / (float)N;
  u4v in = *(const u4v*)(y + (size_t)t4 * 4);
  u4v outv;
#pragma unroll
  for (int i = 0; i < 4; ++i) {
    int col = col0 + i;
    float S = 0.0f, SS = 0.0f;
#pragma unroll
    for (int k = 0; k < 8; ++k) { S += sum[k * 128 + col]; SS += sumsq[k * 128 + col]; }
    float m = S * invN;
    float v = SS * invN - m * m;
    float val = (bf2f(in[i]) - m) * rsqrtf(v + BN_EPS) * g[col] + be[col];
    outv[i] = f2bf(fmaxf(val, 0.0f));
  }
  *(u4v*)(yb + (size_t)t4 * 4) = outv;
}

// ---------- fused BN(train)+ReLU (64 cols, 8 stat slots) + head dot: out = z2@W3+b3
__global__ __launch_bounds__(256) void bn_head_kernel(const float* __restrict__ y2,
    const float* __restrict__ sum, const float* __restrict__ sumsq,
    const float* __restrict__ g, const float* __restrict__ be,
    const float* __restrict__ W3, const float* __restrict__ b3,
    float* __restrict__ out, int N) {
  int wave = threadIdx.x >> 6;
  int lane = threadIdx.x & 63;
  int row = blockIdx.x * 4 + wave;
  if (row >= N) return;
  float S = 0.0f, SS = 0.0f;
#pragma unroll
  for (int k = 0; k < 8; ++k) { S += sum[k * 64 + lane]; SS += sumsq[k * 64 + lane]; }
  float invN = 1.0f / (float)N;
  float m = S * invN;
  float var = SS * invN - m * m;
  float val = (y2[(size_t)row * 64 + lane] - m) * rsqrtf(var + BN_EPS) * g[lane] + be[lane];
  val = fmaxf(val, 0.0f) * W3[lane];
#pragma unroll
  for (int off = 32; off > 0; off >>= 1) val += __shfl_down(val, off);
  if (lane == 0) out[row] = val + b3[0];
}

// ================================================================ launch
extern "C" void kernel_launch(void* const* d_in, const int* in_sizes, int n_in,
                              void* d_out, int out_size, void* d_ws, size_t ws_size,
                              hipStream_t stream) {
  const int F = 100, H = 128;
  const int N = in_sizes[0] / F;
  const int E = in_sizes[1] / 2;

  const float* x   = (const float*)d_in[0];
  const int* edge  = (const int*)d_in[1];
  const int* src   = edge;
  const int* dst   = edge + E;
  const float* Wl1 = (const float*)d_in[2];
  const float* bl1 = (const float*)d_in[3];
  const float* Wr1 = (const float*)d_in[4];
  const float* Wl2 = (const float*)d_in[5];
  const float* bl2 = (const float*)d_in[6];
  const float* Wr2 = (const float*)d_in[7];
  const float* W1  = (const float*)d_in[8];
  const float* b1  = (const float*)d_in[9];
  const float* g1  = (const float*)d_in[10];
  const float* be1 = (const float*)d_in[11];
  const float* W2  = (const float*)d_in[12];
  const float* b2  = (const float*)d_in[13];
  const float* g2  = (const float*)d_in[14];
  const float* be2 = (const float*)d_in[15];
  const float* W3  = (const float*)d_in[16];
  const float* b3  = (const float*)d_in[17];

  float* out0 = (float*)d_out;              // [N]
  float* h1   = out0 + N;                   // [N,128] fp32 (required output)
  float* h2   = h1 + (size_t)N * H;         // [N,128] fp32 (required output)

  const int SCAN_G = (N + 1023) / 1024;     // 49
  const int NB = (N + 127) / 128;           // 391 buckets

  // ---- workspace layout
  char* wsp = (char*)d_ws;
  int* deg       = (int*)wsp;               wsp += (size_t)N * sizeof(int);
  int* row_start = (int*)wsp;               wsp += (size_t)N * sizeof(int);
  int* eidx      = (int*)wsp;               wsp += (size_t)E * sizeof(int);
  unsigned* pairs = (unsigned*)wsp;         wsp += (size_t)E * sizeof(unsigned);
  int* gcursor   = (int*)wsp;               wsp += 512 * sizeof(int);
  int* partials  = (int*)wsp;               wsp += 256 * sizeof(int);
  int* blk_off   = (int*)wsp;               wsp += 256 * sizeof(int);
  float* sum1    = (float*)wsp;             wsp += 8 * 128 * sizeof(float);
  float* sq1     = (float*)wsp;             wsp += 8 * 128 * sizeof(float);
  float* sum2    = (float*)wsp;             wsp += 8 * 64 * sizeof(float);
  float* sq2     = (float*)wsp;             wsp += 8 * 64 * sizeof(float);
  float* bufA    = (float*)wsp;             wsp += (size_t)N * 128 * sizeof(float);
  unsigned short* bfX = (unsigned short*)wsp; wsp += (size_t)N * 128 * 2; // xb -> z1b
  unsigned short* bfM = (unsigned short*)wsp; wsp += (size_t)N * 128 * 2; // mean1b/mean2b
  unsigned short* bfH = (unsigned short*)wsp; wsp += (size_t)N * 128 * 2; // h1b
  unsigned short* Wl1t = (unsigned short*)wsp; wsp += 128 * 128 * 2;
  unsigned short* Wr1t = (unsigned short*)wsp; wsp += 128 * 128 * 2;
  unsigned short* Wl2t = (unsigned short*)wsp; wsp += 128 * 128 * 2;
  unsigned short* Wr2t = (unsigned short*)wsp; wsp += 128 * 128 * 2;
  unsigned short* W1t  = (unsigned short*)wsp; wsp += 128 * 128 * 2;
  unsigned short* W2t  = (unsigned short*)wsp; wsp += 64 * 128 * 2;

  unsigned short* y1b = (unsigned short*)bufA;                    // [N,128] bf16
  float* y2 = (float*)((char*)bufA + (size_t)N * 128 * 2);        // [N,64] fp32

  // ---- zero-init accumulated scratch (ws poisoned 0xAA each call)
  hipMemsetAsync(deg, 0, (size_t)N * sizeof(int), stream);
  hipMemsetAsync(sum1, 0, (8 * 128 + 8 * 128 + 8 * 64 + 8 * 64) * sizeof(float), stream);

  // ---- build CSR (dst -> list of src)
  deg_kernel<<<(E + 255) / 256, 256, 0, stream>>>(dst, deg, E);
  scan_partial_kernel<<<SCAN_G, 256, 0, stream>>>(deg, partials, N);
  scan_offsets_kernel<<<1, 256, 0, stream>>>(partials, blk_off, SCAN_G);
  scan_scatter_kernel<<<SCAN_G, 256, 0, stream>>>(deg, blk_off, row_start, gcursor, N);
  csr_bucket_kernel<<<(E + CHUNK - 1) / CHUNK, 256, 0, stream>>>(src, dst, gcursor, pairs, E);
  csr_fill_kernel<<<NB, 256, 0, stream>>>(pairs, row_start, eidx, N, E);

  // ---- fused bf16 prep (xcast + all weight transposes)
  int xblocks = ((size_t)N * 128 + 255) / 256;
  prep_kernel<<<xblocks + 352, 256, 0, stream>>>(x, bfX,
      Wl1, Wr1, Wl2, Wr2, W1, W2, Wl1t, Wr1t, Wl2t, Wr2t, W1t, W2t, N, xblocks);

  int gemm_grid = (N + 63) / 64;

  // ---- layer 1: gather-mean(xb) -> bfM; sage GEMM -> h1 (fp32) + h1b (bfH)
  gather_kernel<<<(N + 3) / 4, 256, 0, stream>>>(bfX, eidx, row_start, deg, bfM, N);
  wgemm_kernel<8, true, true, true, true, false><<<gemm_grid, 256, 0, stream>>>(
      bfM, Wl1t, bfX, Wr1t, bl1, h1, bfH, nullptr, nullptr, N);

  // ---- layer 2: gather-mean(h1b) -> bfM; fused sage2+MLP1 -> h2, y1b, stats1
  gather_kernel<<<(N + 3) / 4, 256, 0, stream>>>(bfH, eidx, row_start, deg, bfM, N);
  sage_mlp_kernel<<<gemm_grid, 256, 0, stream>>>(
      bfM, Wl2t, bfH, Wr2t, bl2, W1t, b1, h2, y1b, sum1, sq1, N);

  // ---- BN+ReLU -> z1b (bfX)
  bn_relu_kernel<<<((size_t)N * 32 + 255) / 256, 256, 0, stream>>>(
      y1b, N, sum1, sq1, g1, be1, bfX);

  // ---- MLP layer 2: y2 = z1b @ W2 + b2 (fp32) + fused col stats
  wgemm_kernel<4, false, false, true, false, true><<<gemm_grid, 256, 0, stream>>>(
      bfX, W2t, nullptr, nullptr, b2, y2, nullptr, sum2, sq2, N);

  // ---- fused BN+ReLU+head: out = relu(bn(y2)) @ W3 + b3
  bn_head_kernel<<<(N + 3) / 4, 256, 0, stream>>>(
      y2, sum2, sq2, g2, be2, W3, b3, out0, N);
}

// Round 10
// 391.108 us; speedup vs baseline: 1.0021x; 1.0021x over previous
//
#include <hip/hip_runtime.h>

#define BN_EPS 1e-5f

typedef short s8v __attribute__((ext_vector_type(8)));
typedef float f4v __attribute__((ext_vector_type(4)));
typedef unsigned short u8v __attribute__((ext_vector_type(8)));

__device__ __forceinline__ unsigned short f2bf(float f) {
  union { float f; unsigned u; } v; v.f = f;
  unsigned r = v.u + 0x7FFF + ((v.u >> 16) & 1);
  return (unsigned short)(r >> 16);
}
__device__ __forceinline__ float bf2f(unsigned short u) {
  union { unsigned u; float f; } v; v.u = ((unsigned)u) << 16; return v.f;
}

// ---------------------------------------------------------------- degree histogram (int)
__global__ __launch_bounds__(256) void deg_kernel(const int* __restrict__ dst,
                                                  int* __restrict__ deg, int E) {
  int e = blockIdx.x * 256 + threadIdx.x;
  if (e < E) atomicAdd(&deg[dst[e]], 1);
}

// ------------------------------------------- scan pass 1: per-block (1024 elems) totals
__global__ __launch_bounds__(256) void scan_partial_kernel(const int* __restrict__ deg,
    int* __restrict__ partials, int N) {
  __shared__ int sh[256];
  int t = threadIdx.x;
  int base = blockIdx.x * 1024 + t * 4;
  int s = 0;
#pragma unroll
  for (int i = 0; i < 4; ++i) {
    int idx = base + i;
    if (idx < N) s += deg[idx];
  }
  sh[t] = s;
  __syncthreads();
  for (int d = 128; d > 0; d >>= 1) {
    if (t < d) sh[t] += sh[t + d];
    __syncthreads();
  }
  if (t == 0) partials[blockIdx.x] = sh[0];
}

// ------------------------------------------- scan pass 2: exclusive scan of partials
__global__ __launch_bounds__(256) void scan_offsets_kernel(const int* __restrict__ partials,
    int* __restrict__ blk_off, int G) {
  __shared__ int sh[256];
  int t = threadIdx.x;
  sh[t] = (t < G) ? partials[t] : 0;
  __syncthreads();
  for (int d = 1; d < 256; d <<= 1) {
    int v = (t >= d) ? sh[t - d] : 0;
    __syncthreads();
    sh[t] += v;
    __syncthreads();
  }
  if (t < G) blk_off[t] = (t == 0) ? 0 : sh[t - 1];
}

// ----- scan pass 3: block-local exclusive scan + offset -> row_start, bucket cursors
__global__ __launch_bounds__(256) void scan_scatter_kernel(const int* __restrict__ deg,
    const int* __restrict__ blk_off, int* __restrict__ row_start,
    int* __restrict__ gcursor, int N) {
  __shared__ int sh[256];
  int t = threadIdx.x;
  int base = blockIdx.x * 1024 + t * 4;
  int v[4];
#pragma unroll
  for (int i = 0; i < 4; ++i) v[i] = (base + i < N) ? deg[base + i] : 0;
  sh[t] = v[0] + v[1] + v[2] + v[3];
  __syncthreads();
  for (int d = 1; d < 256; d <<= 1) {
    int u = (t >= d) ? sh[t - d] : 0;
    __syncthreads();
    sh[t] += u;
    __syncthreads();
  }
  int off = blk_off[blockIdx.x] + ((t == 0) ? 0 : sh[t - 1]);
#pragma unroll
  for (int i = 0; i < 4; ++i) {
    int idx = base + i;
    if (idx < N) {
      row_start[idx] = off;
      if ((idx & 127) == 0) gcursor[idx >> 7] = off;  // pairs cursor = CSR bucket start
      off += v[i];
    }
  }
}

// ------------------- CSR phase A: LDS-staged bucket scatter (kills partial-line writes)
#define CHUNK 8192
#define NBMAX 512
__global__ __launch_bounds__(256) void csr_bucket_kernel(
    const int* __restrict__ src, const int* __restrict__ dst,
    int* __restrict__ gcursor, unsigned* __restrict__ pairs, int E) {
  __shared__ int h[NBMAX];
  __shared__ int off[NBMAX];
  __shared__ int cnt2[NBMAX];
  __shared__ int gadj[NBMAX];
  __shared__ unsigned pbuf[CHUNK];
  __shared__ unsigned short bidx[CHUNK];
  int t = threadIdx.x;
  int base = blockIdx.x * CHUNK;
  int cnt = min(CHUNK, E - base);
  for (int i = t; i < NBMAX; i += 256) { h[i] = 0; cnt2[i] = 0; }
  __syncthreads();
  for (int i = t; i < cnt; i += 256) atomicAdd(&h[dst[base + i] >> 7], 1);
  __syncthreads();
  off[t] = h[t]; off[t + 256] = h[t + 256];
  __syncthreads();
  for (int d = 1; d < 512; d <<= 1) {
    int v0 = (t >= d) ? off[t - d] : 0;
    int v1 = off[t + 256 - d];
    __syncthreads();
    off[t] += v0; off[t + 256] += v1;
    __syncthreads();
  }
  int e0 = off[t] - h[t];
  int e1 = off[t + 256] - h[t + 256];
  __syncthreads();
  off[t] = e0; off[t + 256] = e1;
  __syncthreads();
  for (int i = t; i < NBMAX; i += 256) {
    int c = h[i];
    if (c > 0) gadj[i] = atomicAdd(&gcursor[i], c) - off[i];
  }
  __syncthreads();
  for (int i = t; i < cnt; i += 256) {
    int s = src[base + i];
    int d = dst[base + i];
    int b = d >> 7;
    int p = off[b] + atomicAdd(&cnt2[b], 1);
    pbuf[p] = (unsigned)s | ((unsigned)d << 16);   // both < 2^16 (N=50000)
    bidx[p] = (unsigned short)b;
  }
  __syncthreads();
  for (int i = t; i < cnt; i += 256)
    pairs[gadj[bidx[i]] + i] = pbuf[i];
}

// ------------------- CSR phase B: one block per bucket, private eidx region, LDS cursors
__global__ __launch_bounds__(256) void csr_fill_kernel(
    const unsigned* __restrict__ pairs, const int* __restrict__ row_start,
    int* __restrict__ eidx, int N, int E) {
  __shared__ int cur[128];
  int b = blockIdx.x;
  int node0 = b << 7;
  int t = threadIdx.x;
  if (t < 128) {
    int node = node0 + t;
    cur[t] = (node < N) ? row_start[node] : 0;
  }
  __syncthreads();
  int pbeg = row_start[node0];
  int pend = (node0 + 128 < N) ? row_start[node0 + 128] : E;
  for (int i = pbeg + t; i < pend; i += 256) {
    unsigned p = pairs[i];
    int pos = atomicAdd(&cur[(int)(p >> 16) - node0], 1);
    eidx[pos] = (int)(p & 0xFFFFu);
  }
}

// --------------- fused prep: xcast (blocks [0,xblocks)) + 6 weight transposes
__global__ __launch_bounds__(256) void prep_kernel(
    const float* __restrict__ x, unsigned short* __restrict__ xb,
    const float* __restrict__ Wl1, const float* __restrict__ Wr1,
    const float* __restrict__ Wl2, const float* __restrict__ Wr2,
    const float* __restrict__ W1, const float* __restrict__ W2,
    unsigned short* __restrict__ Wl1t, unsigned short* __restrict__ Wr1t,
    unsigned short* __restrict__ Wl2t, unsigned short* __restrict__ Wr2t,
    unsigned short* __restrict__ W1t, unsigned short* __restrict__ W2t,
    int N, int xblocks) {
  int blk = blockIdx.x;
  if (blk < xblocks) {
    int t = blk * 256 + threadIdx.x;
    if (t < N * 128) {
      int col = t & 127;
      int n = t >> 7;
      xb[t] = (col < 100) ? f2bf(x[n * 100 + col]) : (unsigned short)0;
    }
    return;
  }
  int w = blk - xblocks;
  const float* W; unsigned short* Wt; int K, C, base;
  if (w < 64)       { W = Wl1; Wt = Wl1t; K = 100; C = 128; base = 0;   }
  else if (w < 128) { W = Wr1; Wt = Wr1t; K = 100; C = 128; base = 64;  }
  else if (w < 192) { W = Wl2; Wt = Wl2t; K = 128; C = 128; base = 128; }
  else if (w < 256) { W = Wr2; Wt = Wr2t; K = 128; C = 128; base = 192; }
  else if (w < 320) { W = W1;  Wt = W1t;  K = 128; C = 128; base = 256; }
  else              { W = W2;  Wt = W2t;  K = 128; C = 64;  base = 320; }
  int t = (w - base) * 256 + threadIdx.x;
  if (t >= C * 128) return;
  int c = t >> 7;
  int k = t & 127;
  Wt[t] = (k < K) ? f2bf(W[k * C + c]) : (unsigned short)0;
}

// ------------------------------------------ gather mean over bf16 rows (1 wave / node)
__global__ __launch_bounds__(256) void gather_kernel(
    const unsigned short* __restrict__ feat, const int* __restrict__ eidx,
    const int* __restrict__ row_start, const int* __restrict__ deg,
    unsigned short* __restrict__ mean_out, int N) {
  int wave = threadIdx.x >> 6;
  int lane = threadIdx.x & 63;
  int node = blockIdx.x * 4 + wave;
  if (node >= N) return;
  int beg = row_start[node];
  int d = deg[node];
  float a0 = 0.0f, a1 = 0.0f;
  for (int i0 = 0; i0 < d; i0 += 64) {
    int cnt = min(64, d - i0);
    int my = (lane < cnt) ? eidx[beg + i0 + lane] : 0;
    int j = 0;
    for (; j + 7 < cnt; j += 8) {
      int s0 = __shfl(my, j + 0);
      int s1 = __shfl(my, j + 1);
      int s2 = __shfl(my, j + 2);
      int s3 = __shfl(my, j + 3);
      int s4 = __shfl(my, j + 4);
      int s5 = __shfl(my, j + 5);
      int s6 = __shfl(my, j + 6);
      int s7 = __shfl(my, j + 7);
      unsigned v0 = ((const unsigned*)(feat + (size_t)s0 * 128))[lane];
      unsigned v1 = ((const unsigned*)(feat + (size_t)s1 * 128))[lane];
      unsigned v2 = ((const unsigned*)(feat + (size_t)s2 * 128))[lane];
      unsigned v3 = ((const unsigned*)(feat + (size_t)s3 * 128))[lane];
      unsigned v4 = ((const unsigned*)(feat + (size_t)s4 * 128))[lane];
      unsigned v5 = ((const unsigned*)(feat + (size_t)s5 * 128))[lane];
      unsigned v6 = ((const unsigned*)(feat + (size_t)s6 * 128))[lane];
      unsigned v7 = ((const unsigned*)(feat + (size_t)s7 * 128))[lane];
      a0 += bf2f((unsigned short)v0) + bf2f((unsigned short)v1)
          + bf2f((unsigned short)v2) + bf2f((unsigned short)v3)
          + bf2f((unsigned short)v4) + bf2f((unsigned short)v5)
          + bf2f((unsigned short)v6) + bf2f((unsigned short)v7);
      a1 += bf2f((unsigned short)(v0 >> 16)) + bf2f((unsigned short)(v1 >> 16))
          + bf2f((unsigned short)(v2 >> 16)) + bf2f((unsigned short)(v3 >> 16))
          + bf2f((unsigned short)(v4 >> 16)) + bf2f((unsigned short)(v5 >> 16))
          + bf2f((unsigned short)(v6 >> 16)) + bf2f((unsigned short)(v7 >> 16));
    }
    for (; j < cnt; ++j) {
      int s0 = __shfl(my, j);
      unsigned v0 = ((const unsigned*)(feat + (size_t)s0 * 128))[lane];
      a0 += bf2f((unsigned short)v0);
      a1 += bf2f((unsigned short)(v0 >> 16));
    }
  }
  float inv = 1.0f / fmaxf((float)d, 1.0f);
  unsigned o = (unsigned)f2bf(a0 * inv) | ((unsigned)f2bf(a1 * inv) << 16);
  ((unsigned*)(mean_out + (size_t)node * 128))[lane] = o;
}

// --------------------- wave-independent MFMA GEMM: 16 rows/wave, direct D-layout stores.
// STATS (R9 lesson): NO global atomics in this kernel -- per-block partials go to a
// private contiguous slot (partial[block][2*COLS]); a tiny reducer kernel finalizes.
// BNIN: apply BN1+ReLU to the A-operand in registers (deletes the bn_relu pass).
template<int CT, bool DUAL, bool RELU, bool F32OUT, bool BF16OUT, bool STATS, bool BNIN>
__global__ __launch_bounds__(256) void wgemm_kernel(
    const unsigned short* __restrict__ A1, const unsigned short* __restrict__ W1t,
    const unsigned short* __restrict__ A2, const unsigned short* __restrict__ W2t,
    const float* __restrict__ bias,
    float* __restrict__ outF, unsigned short* __restrict__ outB,
    float* __restrict__ pout,
    const float* __restrict__ sumIn, const float* __restrict__ sqIn,
    const float* __restrict__ gIn, const float* __restrict__ beIn, int N) {
  const int COLS = CT * 16;
  __shared__ float red[STATS ? 8 * COLS : 1];
  int t = threadIdx.x;
  int wave = t >> 6, lane = t & 63;
  int quad = lane >> 4, m = lane & 15;
  int r0 = blockIdx.x * 64 + wave * 16;
  int ar = min(r0 + m, N - 1);
  float invN = 1.0f / (float)N;

  f4v acc[CT];
#pragma unroll
  for (int ct = 0; ct < CT; ++ct) acc[ct] = (f4v){0.f, 0.f, 0.f, 0.f};

  const unsigned short* a1p = A1 + (size_t)ar * 128 + quad * 8;
  const unsigned short* a2p = DUAL ? (A2 + (size_t)ar * 128 + quad * 8) : nullptr;
#pragma unroll
  for (int k0 = 0; k0 < 128; k0 += 32) {
    s8v a1;
    if (BNIN) {
      u8v raw = *(const u8v*)(a1p + k0);
#pragma unroll
      for (int i = 0; i < 8; ++i) {
        int col = k0 + quad * 8 + i;
        float S = sumIn[col], SS = sqIn[col];
        float mean = S * invN;
        float var = SS * invN - mean * mean;
        float sc = rsqrtf(var + BN_EPS) * gIn[col];
        float sh = beIn[col] - mean * sc;
        float z = fmaxf(bf2f(raw[i]) * sc + sh, 0.0f);
        a1[i] = (short)f2bf(z);
      }
    } else {
      a1 = *(const s8v*)(a1p + k0);
    }
    s8v a2;
    if (DUAL) a2 = *(const s8v*)(a2p + k0);
#pragma unroll
    for (int ct = 0; ct < CT; ++ct) {
      s8v b1 = *(const s8v*)(W1t + (size_t)(ct * 16 + m) * 128 + k0 + quad * 8);
      acc[ct] = __builtin_amdgcn_mfma_f32_16x16x32_bf16(a1, b1, acc[ct], 0, 0, 0);
      if (DUAL) {
        s8v b2 = *(const s8v*)(W2t + (size_t)(ct * 16 + m) * 128 + k0 + quad * 8);
        acc[ct] = __builtin_amdgcn_mfma_f32_16x16x32_bf16(a2, b2, acc[ct], 0, 0, 0);
      }
    }
  }
  // direct epilogue from D-layout: col = ct*16+m, row = quad*4+r
#pragma unroll
  for (int ct = 0; ct < CT; ++ct) {
    int col = ct * 16 + m;
    float b = bias[col];
    float s_ct = 0.0f, ss_ct = 0.0f;
#pragma unroll
    for (int r = 0; r < 4; ++r) {
      int gr = r0 + quad * 4 + r;
      float v = acc[ct][r] + b;
      if (RELU) v = fmaxf(v, 0.0f);
      if (gr < N) {
        if (F32OUT) outF[(size_t)gr * COLS + col] = v;
        if (BF16OUT) outB[(size_t)gr * COLS + col] = f2bf(v);
        if (STATS) { s_ct += v; ss_ct += v * v; }
      }
    }
    if (STATS) {
      s_ct += __shfl_xor(s_ct, 16);  s_ct += __shfl_xor(s_ct, 32);
      ss_ct += __shfl_xor(ss_ct, 16); ss_ct += __shfl_xor(ss_ct, 32);
      if (quad == 0) {
        red[wave * COLS + col] = s_ct;
        red[4 * COLS + wave * COLS + col] = ss_ct;
      }
    }
  }
  if (STATS) {
    __syncthreads();
    if (t < COLS) {
      float S = 0.0f, SS = 0.0f;
#pragma unroll
      for (int w = 0; w < 4; ++w) {
        S  += red[w * COLS + t];
        SS += red[4 * COLS + w * COLS + t];
      }
      pout[(size_t)blockIdx.x * 2 * COLS + t] = S;
      pout[(size_t)blockIdx.x * 2 * COLS + COLS + t] = SS;
    }
  }
}

// ------------- fused sage2 + MLP1, wave-independent; stats -> block partials (no atomics)
__global__ __launch_bounds__(256) void sage_mlp_kernel(
    const unsigned short* __restrict__ A1,   // mean2b
    const unsigned short* __restrict__ Wlt,
    const unsigned short* __restrict__ A2,   // h1b (self)
    const unsigned short* __restrict__ Wrt,
    const float* __restrict__ bl,
    const unsigned short* __restrict__ W1t, const float* __restrict__ b1,
    float* __restrict__ h2out, unsigned short* __restrict__ y1b,
    float* __restrict__ pout, int N) {
  const int TS = 136;                        // bf16 strip stride: 16B-aligned rows
  __shared__ unsigned short tb[4][16 * TS];  // 17408 B, per-wave private
  __shared__ float red[8 * 128];             // stats staging
  int t = threadIdx.x;
  int wave = t >> 6, lane = t & 63;
  int quad = lane >> 4, m = lane & 15;
  int r0 = blockIdx.x * 64 + wave * 16;
  int ar = min(r0 + m, N - 1);

  // ---- phase 1: sage2 dual GEMM
  f4v acc[8];
#pragma unroll
  for (int ct = 0; ct < 8; ++ct) acc[ct] = (f4v){0.f, 0.f, 0.f, 0.f};
  {
    const unsigned short* a1p = A1 + (size_t)ar * 128 + quad * 8;
    const unsigned short* a2p = A2 + (size_t)ar * 128 + quad * 8;
#pragma unroll
    for (int k0 = 0; k0 < 128; k0 += 32) {
      s8v a1 = *(const s8v*)(a1p + k0);
      s8v a2 = *(const s8v*)(a2p + k0);
#pragma unroll
      for (int ct = 0; ct < 8; ++ct) {
        s8v b1 = *(const s8v*)(Wlt + (size_t)(ct * 16 + m) * 128 + k0 + quad * 8);
        acc[ct] = __builtin_amdgcn_mfma_f32_16x16x32_bf16(a1, b1, acc[ct], 0, 0, 0);
        s8v b2 = *(const s8v*)(Wrt + (size_t)(ct * 16 + m) * 128 + k0 + quad * 8);
        acc[ct] = __builtin_amdgcn_mfma_f32_16x16x32_bf16(a2, b2, acc[ct], 0, 0, 0);
      }
    }
  }
  // ---- epilogue 1: h2 fp32 direct store + bf16 into private strip
#pragma unroll
  for (int ct = 0; ct < 8; ++ct) {
    int col = ct * 16 + m;
    float b = bl[col];
#pragma unroll
    for (int r = 0; r < 4; ++r) {
      int lr = quad * 4 + r;
      int gr = r0 + lr;
      float v = fmaxf(acc[ct][r] + b, 0.0f);
      if (gr < N) h2out[(size_t)gr * 128 + col] = v;
      tb[wave][lr * TS + col] = f2bf(v);
    }
  }
  // ---- D->A transpose read (same wave; compiler inserts lgkmcnt wait)
  s8v af[4];
#pragma unroll
  for (int kk = 0; kk < 4; ++kk)
    af[kk] = *(const s8v*)&tb[wave][m * TS + kk * 32 + quad * 8];

  // ---- phase 2: y1 = h2b @ W1 + b1 (reuse acc)
#pragma unroll
  for (int ct = 0; ct < 8; ++ct) acc[ct] = (f4v){0.f, 0.f, 0.f, 0.f};
#pragma unroll
  for (int kk = 0; kk < 4; ++kk) {
    int k0 = kk * 32;
#pragma unroll
    for (int ct = 0; ct < 8; ++ct) {
      s8v bv = *(const s8v*)(W1t + (size_t)(ct * 16 + m) * 128 + k0 + quad * 8);
      acc[ct] = __builtin_amdgcn_mfma_f32_16x16x32_bf16(af[kk], bv, acc[ct], 0, 0, 0);
    }
  }
  // ---- epilogue 2: y1b bf16 direct store + col stats (block partials, NO atomics)
#pragma unroll
  for (int ct = 0; ct < 8; ++ct) {
    int col = ct * 16 + m;
    float b = b1[col];
    float s_ct = 0.0f, ss_ct = 0.0f;
#pragma unroll
    for (int r = 0; r < 4; ++r) {
      int gr = r0 + quad * 4 + r;
      float v = acc[ct][r] + b;
      if (gr < N) {
        y1b[(size_t)gr * 128 + col] = f2bf(v);
        s_ct += v; ss_ct += v * v;
      }
    }
    s_ct += __shfl_xor(s_ct, 16);  s_ct += __shfl_xor(s_ct, 32);
    ss_ct += __shfl_xor(ss_ct, 16); ss_ct += __shfl_xor(ss_ct, 32);
    if (quad == 0) {
      red[wave * 128 + col] = s_ct;
      red[512 + wave * 128 + col] = ss_ct;
    }
  }
  __syncthreads();
  if (t < 128) {
    float S = red[t] + red[128 + t] + red[256 + t] + red[384 + t];
    float SS = red[512 + t] + red[640 + t] + red[768 + t] + red[896 + t];
    pout[(size_t)blockIdx.x * 256 + t] = S;
    pout[(size_t)blockIdx.x * 256 + 128 + t] = SS;
  }
}

// ---------------- hierarchical stats reducer: partial[nb][2*COLS] -> sum[COLS], sq[COLS]
// 16 blocks; only 16*(256/COLS) low-contention atomics per column.
template<int COLS>
__global__ __launch_bounds__(256) void reduce_stats_kernel(
    const float* __restrict__ p, int nb, float* __restrict__ sum, float* __restrict__ sq) {
  const int H = 256 / COLS;
  int t = threadIdx.x;
  int col = t % COLS;
  int h = t / COLS;
  int slices = 16 * H;
  int per = (nb + slices - 1) / slices;
  int r0 = (blockIdx.x * H + h) * per;
  int r1 = min(r0 + per, nb);
  float S = 0.0f, SS = 0.0f;
  for (int r = r0; r < r1; ++r) {
    S  += p[(size_t)r * 2 * COLS + col];
    SS += p[(size_t)r * 2 * COLS + COLS + col];
  }
  atomicAdd(&sum[col], S);
  atomicAdd(&sq[col], SS);
}

// ---------- fused BN2(train)+ReLU (single-slot stats) + head dot: out = z2@W3+b3
__global__ __launch_bounds__(256) void bn_head_kernel(const float* __restrict__ y2,
    const float* __restrict__ sum, const float* __restrict__ sumsq,
    const float* __restrict__ g, const float* __restrict__ be,
    const float* __restrict__ W3, const float* __restrict__ b3,
    float* __restrict__ out, int N) {
  int wave = threadIdx.x >> 6;
  int lane = threadIdx.x & 63;
  int row = blockIdx.x * 4 + wave;
  if (row >= N) return;
  float invN = 1.0f / (float)N;
  float m = sum[lane] * invN;
  float var = sumsq[lane] * invN - m * m;
  float val = (y2[(size_t)row * 64 + lane] - m) * rsqrtf(var + BN_EPS) * g[lane] + be[lane];
  val = fmaxf(val, 0.0f) * W3[lane];
#pragma unroll
  for (int off = 32; off > 0; off >>= 1) val += __shfl_down(val, off);
  if (lane == 0) out[row] = val + b3[0];
}

// ================================================================ launch
extern "C" void kernel_launch(void* const* d_in, const int* in_sizes, int n_in,
                              void* d_out, int out_size, void* d_ws, size_t ws_size,
                              hipStream_t stream) {
  const int F = 100, H = 128;
  const int N = in_sizes[0] / F;
  const int E = in_sizes[1] / 2;

  const float* x   = (const float*)d_in[0];
  const int* edge  = (const int*)d_in[1];
  const int* src   = edge;
  const int* dst   = edge + E;
  const float* Wl1 = (const float*)d_in[2];
  const float* bl1 = (const float*)d_in[3];
  const float* Wr1 = (const float*)d_in[4];
  const float* Wl2 = (const float*)d_in[5];
  const float* bl2 = (const float*)d_in[6];
  const float* Wr2 = (const float*)d_in[7];
  const float* W1  = (const float*)d_in[8];
  const float* b1  = (const float*)d_in[9];
  const float* g1  = (const float*)d_in[10];
  const float* be1 = (const float*)d_in[11];
  const float* W2  = (const float*)d_in[12];
  const float* b2  = (const float*)d_in[13];
  const float* g2  = (const float*)d_in[14];
  const float* be2 = (const float*)d_in[15];
  const float* W3  = (const float*)d_in[16];
  const float* b3  = (const float*)d_in[17];

  float* out0 = (float*)d_out;              // [N]
  float* h1   = out0 + N;                   // [N,128] fp32 (required output)
  float* h2   = h1 + (size_t)N * H;         // [N,128] fp32 (required output)

  const int SCAN_G = (N + 1023) / 1024;     // 49
  const int NB = (N + 127) / 128;           // 391 buckets
  const int GG = (N + 63) / 64;             // 782 GEMM blocks

  // ---- workspace layout
  char* wsp = (char*)d_ws;
  int* deg       = (int*)wsp;               wsp += (size_t)N * sizeof(int);
  int* row_start = (int*)wsp;               wsp += (size_t)N * sizeof(int);
  int* eidx      = (int*)wsp;               wsp += (size_t)E * sizeof(int);
  unsigned* pairs = (unsigned*)wsp;         wsp += (size_t)E * sizeof(unsigned);
  int* gcursor   = (int*)wsp;               wsp += 512 * sizeof(int);
  int* partials  = (int*)wsp;               wsp += 256 * sizeof(int);
  int* blk_off   = (int*)wsp;               wsp += 256 * sizeof(int);
  float* sum1    = (float*)wsp;             wsp += 128 * sizeof(float);
  float* sq1     = (float*)wsp;             wsp += 128 * sizeof(float);
  float* sum2    = (float*)wsp;             wsp += 64 * sizeof(float);
  float* sq2     = (float*)wsp;             wsp += 64 * sizeof(float);
  float* part1   = (float*)wsp;             wsp += (size_t)GG * 256 * sizeof(float);
  float* part2   = (float*)wsp;             wsp += (size_t)GG * 128 * sizeof(float);
  float* bufA    = (float*)wsp;             wsp += (size_t)N * 128 * sizeof(float);
  unsigned short* bfX = (unsigned short*)wsp; wsp += (size_t)N * 128 * 2; // xb
  unsigned short* bfM = (unsigned short*)wsp; wsp += (size_t)N * 128 * 2; // mean1b/mean2b
  unsigned short* bfH = (unsigned short*)wsp; wsp += (size_t)N * 128 * 2; // h1b
  unsigned short* Wl1t = (unsigned short*)wsp; wsp += 128 * 128 * 2;
  unsigned short* Wr1t = (unsigned short*)wsp; wsp += 128 * 128 * 2;
  unsigned short* Wl2t = (unsigned short*)wsp; wsp += 128 * 128 * 2;
  unsigned short* Wr2t = (unsigned short*)wsp; wsp += 128 * 128 * 2;
  unsigned short* W1t  = (unsigned short*)wsp; wsp += 128 * 128 * 2;
  unsigned short* W2t  = (unsigned short*)wsp; wsp += 64 * 128 * 2;

  unsigned short* y1b = (unsigned short*)bufA;                    // [N,128] bf16
  float* y2 = (float*)((char*)bufA + (size_t)N * 128 * 2);        // [N,64] fp32

  // ---- zero-init accumulated scratch (ws poisoned 0xAA each call)
  hipMemsetAsync(deg, 0, (size_t)N * sizeof(int), stream);
  hipMemsetAsync(sum1, 0, 384 * sizeof(float), stream);

  // ---- build CSR (dst -> list of src)
  deg_kernel<<<(E + 255) / 256, 256, 0, stream>>>(dst, deg, E);
  scan_partial_kernel<<<SCAN_G, 256, 0, stream>>>(deg, partials, N);
  scan_offsets_kernel<<<1, 256, 0, stream>>>(partials, blk_off, SCAN_G);
  scan_scatter_kernel<<<SCAN_G, 256, 0, stream>>>(deg, blk_off, row_start, gcursor, N);
  csr_bucket_kernel<<<(E + CHUNK - 1) / CHUNK, 256, 0, stream>>>(src, dst, gcursor, pairs, E);
  csr_fill_kernel<<<NB, 256, 0, stream>>>(pairs, row_start, eidx, N, E);

  // ---- fused bf16 prep (xcast + all weight transposes)
  int xblocks = ((size_t)N * 128 + 255) / 256;
  prep_kernel<<<xblocks + 352, 256, 0, stream>>>(x, bfX,
      Wl1, Wr1, Wl2, Wr2, W1, W2, Wl1t, Wr1t, Wl2t, Wr2t, W1t, W2t, N, xblocks);

  // ---- layer 1: gather-mean(xb) -> bfM; sage GEMM -> h1 (fp32) + h1b (bfH)
  gather_kernel<<<(N + 3) / 4, 256, 0, stream>>>(bfX, eidx, row_start, deg, bfM, N);
  wgemm_kernel<8, true, true, true, true, false, false><<<GG, 256, 0, stream>>>(
      bfM, Wl1t, bfX, Wr1t, bl1, h1, bfH, nullptr, nullptr, nullptr, nullptr, nullptr, N);

  // ---- layer 2: gather-mean(h1b) -> bfM; fused sage2+MLP1 -> h2, y1b, part1
  gather_kernel<<<(N + 3) / 4, 256, 0, stream>>>(bfH, eidx, row_start, deg, bfM, N);
  sage_mlp_kernel<<<GG, 256, 0, stream>>>(
      bfM, Wl2t, bfH, Wr2t, bl2, W1t, b1, h2, y1b, part1, N);

  // ---- finalize BN1 stats
  reduce_stats_kernel<128><<<16, 256, 0, stream>>>(part1, GG, sum1, sq1);

  // ---- MLP2 with fused BN1+ReLU on input: y2 = relu(bn(y1)) @ W2 + b2 ; part2
  wgemm_kernel<4, false, false, true, false, true, true><<<GG, 256, 0, stream>>>(
      y1b, W2t, nullptr, nullptr, b2, y2, nullptr, part2, sum1, sq1, g1, be1, N);

  // ---- finalize BN2 stats
  reduce_stats_kernel<64><<<16, 256, 0, stream>>>(part2, GG, sum2, sq2);

  // ---- fused BN2+ReLU+head: out = relu(bn(y2)) @ W3 + b3
  bn_head_kernel<<<(N + 3) / 4, 256, 0, stream>>>(
      y2, sum2, sq2, g2, be2, W3, b3, out0, N);
}